// Round 1
// baseline (243.440 us; speedup 1.0000x reference)
//
#include <hip/hip_runtime.h>

// Laplacian3D: x shape (8, 1, 192, 192, 192) fp32, 7-point stencil, zero pad.
// cx = cy = cz = 1/0.01^2 = 1e4 ; c0 = -6e4.
// Memory-bound: 226.5 MB in + 226.5 MB out -> roofline ~72 us @ 6.3 TB/s.

#define DIM_W 192
#define DIM_H 192
#define DIM_D 192
#define W4    (DIM_W / 4)   // 48 float4 per row

__global__ __launch_bounds__(256) void lap3d_kernel(
    const float* __restrict__ x, float* __restrict__ out, int total4)
{
    int idx4 = blockIdx.x * blockDim.x + threadIdx.x;
    if (idx4 >= total4) return;

    int w4 = idx4 % W4;
    int t  = idx4 / W4;
    int h  = t % DIM_H;
    t /= DIM_H;
    int d  = t % DIM_D;
    // batch index implicit: neighbors never cross batch since d guards do it.

    const float4* __restrict__ xc = reinterpret_cast<const float4*>(x);

    const float cx = 10000.0f;   // D axis
    const float cy = 10000.0f;   // H axis
    const float cz = 10000.0f;   // W axis
    const float c0 = -60000.0f;

    const float4 zero = make_float4(0.f, 0.f, 0.f, 0.f);

    float4 c  = xc[idx4];
    float4 dm = (d > 0)         ? xc[idx4 - W4 * DIM_H] : zero;
    float4 dp = (d < DIM_D - 1) ? xc[idx4 + W4 * DIM_H] : zero;
    float4 hm = (h > 0)         ? xc[idx4 - W4]         : zero;
    float4 hp = (h < DIM_H - 1) ? xc[idx4 + W4]         : zero;

    long base = (long)idx4 * 4;
    float l = (w4 > 0)      ? x[base - 1] : 0.f;
    float r = (w4 < W4 - 1) ? x[base + 4] : 0.f;

    // W-axis shifted vectors
    float4 wm = make_float4(l,   c.x, c.y, c.z);
    float4 wp = make_float4(c.y, c.z, c.w, r);

    float4 o;
    o.x = c0 * c.x + cx * (dm.x + dp.x) + cy * (hm.x + hp.x) + cz * (wm.x + wp.x);
    o.y = c0 * c.y + cx * (dm.y + dp.y) + cy * (hm.y + hp.y) + cz * (wm.y + wp.y);
    o.z = c0 * c.z + cx * (dm.z + dp.z) + cy * (hm.z + hp.z) + cz * (wm.z + wp.z);
    o.w = c0 * c.w + cx * (dm.w + dp.w) + cy * (hm.w + hp.w) + cz * (wm.w + wp.w);

    reinterpret_cast<float4*>(out)[idx4] = o;
}

extern "C" void kernel_launch(void* const* d_in, const int* in_sizes, int n_in,
                              void* d_out, int out_size, void* d_ws, size_t ws_size,
                              hipStream_t stream)
{
    const float* x = (const float*)d_in[0];
    float* out = (float*)d_out;

    int total4 = out_size / 4;            // 14,155,776 float4
    int block = 256;
    int grid = (total4 + block - 1) / block;

    lap3d_kernel<<<grid, block, 0, stream>>>(x, out, total4);
}

// Round 2
// 113.721 us; speedup vs baseline: 2.1407x; 2.1407x over previous
//
#include <hip/hip_runtime.h>

// Laplacian3D (8,1,192,192,192) fp32, 7-point, zero pad. cx=cy=cz=1e4, c0=-6e4.
// Round 2: 3-plane rotating LDS march along D.
//   - block owns (b, 16-row h-tile, 24-plane d-chunk); marches d.
//   - center d-1/d kept in registers; one new plane staged to LDS per step.
//   - rows padded with a zero float4 each side -> unconditional aligned b128
//     halo reads, zero strided scalar loads.
// Global bytes/output: ~18B read + 16B write (was 104B through L1).

#define TH    16            // h rows per block
#define TD    24            // d planes per block
#define NH    12            // 192 / TH
#define ND    8             // 192 / TD
#define W4    48            // 192 floats = 48 float4 per row
#define NROWS 18            // TH + 2 halo rows
#define ROWP  50            // padded row width in float4 (zero pad col each side)
#define PLANE_LDS (NROWS * ROWP)   // 900 float4 = 14400 B
#define SITEMS (NROWS * W4)        // 864 float4 staged per plane
#define PS4   9216          // plane stride in float4 (192*48)
#define BS4   (192 * PS4)   // batch stride in float4

__global__ __launch_bounds__(256) void lap3d_kernel(
    const float4* __restrict__ x, float4* __restrict__ out)
{
    __shared__ float4 buf[3][PLANE_LDS];   // 43,200 B -> 3 blocks/CU

    const int tid = threadIdx.x;
    const int h0 = blockIdx.x * TH;
    const int d0 = blockIdx.y * TD;
    const int b  = blockIdx.z;

    const float cc = 10000.0f;
    const float c0 = -60000.0f;
    const float4 zero4 = make_float4(0.f, 0.f, 0.f, 0.f);

    // zero the pad columns once (never overwritten by staging)
    for (int i = tid; i < 3 * NROWS * 2; i += 256) {
        int s = i / (NROWS * 2);
        int r = (i >> 1) % NROWS;
        buf[s][r * ROWP + ((i & 1) ? (ROWP - 1) : 0)] = zero4;
    }

    // -------- staging metadata (4 items/thread, 864 total) --------
    int  g_base[4], l_off[4];
    bool v_h[4], wr[4];
    #pragma unroll
    for (int k = 0; k < 4; ++k) {
        int j  = tid + k * 256;
        int lr = j / W4;
        int w4 = j - lr * W4;
        int gh = h0 - 1 + lr;
        wr[k]  = (j < SITEMS);
        v_h[k] = wr[k] && (gh >= 0) && (gh < 192);
        int ghc = min(max(gh, 0), 191);
        g_base[k] = b * BS4 + ghc * W4 + w4;   // + plane*PS4 later
        l_off[k]  = lr * ROWP + 1 + w4;
    }

    // -------- output metadata (3 items/thread, 768 total) --------
    int o_base[3], cof[3], mof[3], pof[3];
    float4 r_dm[3], r_c[3];
    #pragma unroll
    for (int k = 0; k < 3; ++k) {
        int o  = tid + k * 256;
        int hl = o / W4;
        int w4 = o - hl * W4;
        o_base[k] = b * BS4 + (h0 + hl) * W4 + w4;   // + d*PS4 later
        cof[k] = (hl + 1) * ROWP + 1 + w4;   // center row in LDS plane
        mof[k] = (hl + 0) * ROWP + 1 + w4;   // h-1 halo row
        pof[k] = (hl + 2) * ROWP + 1 + w4;   // h+1 halo row
    }

    // -------- prologue: registers d0-1, d0; stage planes d0, d0+1 --------
    #pragma unroll
    for (int k = 0; k < 3; ++k) {
        r_dm[k] = (d0 > 0) ? x[o_base[k] + (d0 - 1) * PS4] : zero4;
        r_c[k]  = x[o_base[k] + d0 * PS4];
    }
    #pragma unroll
    for (int p = 0; p < 2; ++p) {
        int dpl = d0 + p;            // <= 169, always in range
        int s   = dpl % 3;
        #pragma unroll
        for (int k = 0; k < 4; ++k) {
            if (wr[k]) {
                float4 v = v_h[k] ? x[g_base[k] + dpl * PS4] : zero4;
                buf[s][l_off[k]] = v;
            }
        }
    }
    __syncthreads();

    // -------- main D-march --------
    for (int d = d0; d < d0 + TD; ++d) {
        const int  ds   = d + 2;
        const bool dsok = (ds < 192);

        // (1) issue next-plane global loads early (latency hides under compute)
        float4 sv[4];
        #pragma unroll
        for (int k = 0; k < 4; ++k)
            sv[k] = (v_h[k] && dsok) ? x[g_base[k] + ds * PS4] : zero4;

        // (2) compute from LDS planes d (halos) and d+1 (dp), registers for d-1, d
        const float4* __restrict__ bc = buf[d % 3];
        const float4* __restrict__ bn = buf[(d + 1) % 3];
        #pragma unroll
        for (int k = 0; k < 3; ++k) {
            float4 dpv = bn[cof[k]];
            float4 hmv = bc[mof[k]];
            float4 hpv = bc[pof[k]];
            float4 cl  = bc[cof[k] - 1];
            float4 cr  = bc[cof[k] + 1];
            float4 c = r_c[k], dm = r_dm[k];
            float4 o4;
            o4.x = c0 * c.x + cc * ((dm.x + dpv.x) + (hmv.x + hpv.x) + (cl.w + c.y));
            o4.y = c0 * c.y + cc * ((dm.y + dpv.y) + (hmv.y + hpv.y) + (c.x  + c.z));
            o4.z = c0 * c.z + cc * ((dm.z + dpv.z) + (hmv.z + hpv.z) + (c.y  + c.w));
            o4.w = c0 * c.w + cc * ((dm.w + dpv.w) + (hmv.w + hpv.w) + (c.z  + cr.x));
            out[o_base[k] + d * PS4] = o4;
            r_dm[k] = c;
            r_c[k]  = dpv;
        }

        // (3) commit staged plane d+2 (target buffer untouched this iter)
        const int s = ds % 3;
        #pragma unroll
        for (int k = 0; k < 4; ++k)
            if (wr[k]) buf[s][l_off[k]] = sv[k];

        // (4) one barrier per step
        __syncthreads();
    }
}

extern "C" void kernel_launch(void* const* d_in, const int* in_sizes, int n_in,
                              void* d_out, int out_size, void* d_ws, size_t ws_size,
                              hipStream_t stream)
{
    const float4* x = (const float4*)d_in[0];
    float4* o = (float4*)d_out;
    dim3 grid(NH, ND, 8);   // 12 x 8 x 8 = 768 blocks = 3/CU
    lap3d_kernel<<<grid, dim3(256), 0, stream>>>(x, o);
}

// Round 3
// 98.656 us; speedup vs baseline: 2.4676x; 1.1527x over previous
//
#include <hip/hip_runtime.h>

// Laplacian3D (8,1,192,192,192) fp32, 7-point, zero pad. cx=cy=cz=1e4, c0=-6e4.
// Round 3: 2-plane rotating LDS (halos only) + one-full-step prefetch.
//   - dp comes from per-thread own-position prefetch registers (not LDS),
//     so LDS holds only the current plane's h/w-halo copy -> 2 buffers, 28.8 KB.
//   - loads issued at step d are for plane d+2: consumed & committed at d+1,
//     giving a full step of HBM latency budget.
//   - TD=12 -> 1536 blocks = 6/CU; __launch_bounds__(256,4) for 16 waves/CU.

#define TH    16            // h rows per block
#define TD    12            // d planes per block
#define NH    12            // 192 / TH
#define ND    16            // 192 / TD
#define W4    48            // 48 float4 per row
#define NROWS 18            // TH + 2 halo rows
#define ROWP  50            // padded row width in float4 (zero col each side)
#define PLANE (NROWS * ROWP)   // 900 float4 = 14400 B
#define PS4   9216          // plane stride in float4
#define BS4   (192 * PS4)   // batch stride in float4

__global__ __launch_bounds__(256, 4) void lap3d_kernel(
    const float4* __restrict__ x, float4* __restrict__ out)
{
    __shared__ float4 buf[2][PLANE];   // 28,800 B

    const int tid = threadIdx.x;
    const int h0 = blockIdx.x * TH;
    const int d0 = blockIdx.y * TD;
    const int b  = blockIdx.z;

    const float cc = 10000.0f;
    const float c0 = -60000.0f;
    const float4 zero4 = make_float4(0.f, 0.f, 0.f, 0.f);

    // zero the pad columns once (72 items, never overwritten)
    if (tid < 72) {
        int s = tid / 36;
        int r = (tid >> 1) % 18;
        buf[s][r * ROWP + ((tid & 1) ? ROWP - 1 : 0)] = zero4;
    }

    // -------- per-thread output metadata (3 outputs/thread) --------
    int o_base[3], cof[3], mof[3], pof[3];
    #pragma unroll
    for (int k = 0; k < 3; ++k) {
        int o  = tid + k * 256;
        int hl = o / W4;
        int w4 = o - hl * W4;
        o_base[k] = b * BS4 + (h0 + hl) * W4 + w4;    // + d*PS4 later
        cof[k] = (hl + 1) * ROWP + 1 + w4;
        mof[k] = cof[k] - ROWP;
        pof[k] = cof[k] + ROWP;
    }

    // -------- halo-row staging metadata (threads 0..95) --------
    const bool hact = tid < 96;
    const int  hrow = (tid >= 48);                 // 0 -> h0-1, 1 -> h0+TH
    const int  gh   = h0 + (hrow ? TH : -1);
    const bool hval = hact && (gh >= 0) && (gh < 192);
    const int  ghc  = min(max(gh, 0), 191);
    const int  hw4  = tid % 48;
    const int  hg_base = b * BS4 + ghc * W4 + hw4;
    const int  hl_off  = (hrow ? (TH + 1) : 0) * ROWP + 1 + hw4;

    // -------- prologue --------
    float4 r_dm[3], r_c[3], nxP[3], hvP;
    #pragma unroll
    for (int k = 0; k < 3; ++k) {
        r_dm[k] = (d0 > 0) ? x[o_base[k] + (d0 - 1) * PS4] : zero4;
        r_c[k]  = x[o_base[k] + d0 * PS4];
    }
    hvP = hval ? x[hg_base + d0 * PS4] : zero4;    // plane d0 halo
    {
        float4* bw = buf[d0 & 1];
        #pragma unroll
        for (int k = 0; k < 3; ++k) bw[cof[k]] = r_c[k];
        if (hact) bw[hl_off] = hvP;
    }
    // issue plane d0+1 (d0 <= 180, so always in range)
    #pragma unroll
    for (int k = 0; k < 3; ++k) nxP[k] = x[o_base[k] + (d0 + 1) * PS4];
    hvP = hval ? x[hg_base + (d0 + 1) * PS4] : zero4;
    __syncthreads();

    // -------- main D-march --------
    for (int d = d0; d < d0 + TD; ++d) {
        // (1) issue loads for plane d+2 (consumed & committed at step d+1)
        const int  pl2   = d + 2;
        const bool issue = (pl2 <= d0 + TD) && (pl2 < 192);
        float4 nxN[3], hvN;
        if (issue) {
            #pragma unroll
            for (int k = 0; k < 3; ++k) nxN[k] = x[o_base[k] + pl2 * PS4];
            hvN = hval ? x[hg_base + pl2 * PS4] : zero4;
        } else {
            #pragma unroll
            for (int k = 0; k < 3; ++k) nxN[k] = zero4;
            hvN = zero4;
        }

        // (2) compute step d: halos from LDS plane d, dm/c from regs, dp from nxP
        const float4* __restrict__ bc = buf[d & 1];
        #pragma unroll
        for (int k = 0; k < 3; ++k) {
            float4 dp = nxP[k];
            float4 hm = bc[mof[k]];
            float4 hp = bc[pof[k]];
            float4 cl = bc[cof[k] - 1];
            float4 cr = bc[cof[k] + 1];
            float4 c = r_c[k], dm = r_dm[k];
            float4 o4;
            o4.x = c0 * c.x + cc * ((dm.x + dp.x) + (hm.x + hp.x) + (cl.w + c.y));
            o4.y = c0 * c.y + cc * ((dm.y + dp.y) + (hm.y + hp.y) + (c.x  + c.z));
            o4.z = c0 * c.z + cc * ((dm.z + dp.z) + (hm.z + hp.z) + (c.y  + c.w));
            o4.w = c0 * c.w + cc * ((dm.w + dp.w) + (hm.w + hp.w) + (c.z  + cr.x));
            out[o_base[k] + d * PS4] = o4;
            r_dm[k] = c;
            r_c[k]  = dp;
        }

        // (3) commit plane d+1 (loaded last step) into the other buffer
        float4* bw = buf[(d + 1) & 1];
        #pragma unroll
        for (int k = 0; k < 3; ++k) bw[cof[k]] = nxP[k];
        if (hact) bw[hl_off] = hvP;
        __syncthreads();

        // (4) rotate prefetch registers
        #pragma unroll
        for (int k = 0; k < 3; ++k) nxP[k] = nxN[k];
        hvP = hvN;
    }
}

extern "C" void kernel_launch(void* const* d_in, const int* in_sizes, int n_in,
                              void* d_out, int out_size, void* d_ws, size_t ws_size,
                              hipStream_t stream)
{
    const float4* x = (const float4*)d_in[0];
    float4* o = (float4*)d_out;
    dim3 grid(NH, ND, 8);   // 12 x 16 x 8 = 1536 blocks
    lap3d_kernel<<<grid, dim3(256), 0, stream>>>(x, o);
}

// Round 5
// 78.597 us; speedup vs baseline: 3.0973x; 1.2552x over previous
//
#include <hip/hip_runtime.h>

// Laplacian3D (8,1,192,192,192) fp32, 7-point, zero pad. cx=cy=cz=1e4, c0=-6e4.
// Round 5 (= round 4 with the nontemporal-store type fixed):
//   - TD=24 -> grid 12x8x8 = 768 blocks = exactly 3/CU, all resident, no tail.
//   - 2-plane rotating LDS (h/w halos only), own-position dp from prefetch regs.
//   - prefetch distance = 1 full step; 3 independent blocks/CU overlap latency.
//   - nontemporal stores via ext_vector_type(4) float (HIP_vector_type is
//     rejected by __builtin_nontemporal_store).

#define TH    16            // h rows per block
#define TD    24            // d planes per block
#define NH    12            // 192 / TH
#define ND    8             // 192 / TD
#define W4    48            // 48 float4 per row
#define NROWS 18            // TH + 2 halo rows
#define ROWP  50            // padded row width in float4 (zero col each side)
#define PLANE (NROWS * ROWP)   // 900 float4 = 14400 B
#define PS4   9216          // plane stride in float4
#define BS4   (192 * PS4)   // batch stride in float4

typedef float nfloat4 __attribute__((ext_vector_type(4)));

__global__ __launch_bounds__(256, 3) void lap3d_kernel(
    const float4* __restrict__ x, float4* __restrict__ out)
{
    __shared__ float4 buf[2][PLANE];   // 28,800 B -> 3 blocks/CU

    const int tid = threadIdx.x;
    const int h0 = blockIdx.x * TH;
    const int d0 = blockIdx.y * TD;
    const int b  = blockIdx.z;

    const float cc = 10000.0f;
    const float c0 = -60000.0f;
    const float4 zero4 = make_float4(0.f, 0.f, 0.f, 0.f);

    // zero the pad columns once (72 items, never overwritten)
    if (tid < 72) {
        int s = tid / 36;
        int r = (tid >> 1) % 18;
        buf[s][r * ROWP + ((tid & 1) ? ROWP - 1 : 0)] = zero4;
    }

    // -------- per-thread output metadata (3 outputs/thread) --------
    int o_base[3], cof[3], mof[3], pof[3];
    #pragma unroll
    for (int k = 0; k < 3; ++k) {
        int o  = tid + k * 256;
        int hl = o / W4;
        int w4 = o - hl * W4;
        o_base[k] = b * BS4 + (h0 + hl) * W4 + w4;    // + d*PS4 later
        cof[k] = (hl + 1) * ROWP + 1 + w4;
        mof[k] = cof[k] - ROWP;
        pof[k] = cof[k] + ROWP;
    }

    // -------- halo-row staging metadata (threads 0..95) --------
    const bool hact = tid < 96;
    const int  hrow = (tid >= 48);                 // 0 -> h0-1, 1 -> h0+TH
    const int  gh   = h0 + (hrow ? TH : -1);
    const bool hval = hact && (gh >= 0) && (gh < 192);
    const int  ghc  = min(max(gh, 0), 191);
    const int  hw4  = tid % 48;
    const int  hg_base = b * BS4 + ghc * W4 + hw4;
    const int  hl_off  = (hrow ? (TH + 1) : 0) * ROWP + 1 + hw4;

    // -------- prologue --------
    float4 r_dm[3], r_c[3], nxP[3], hvP;
    #pragma unroll
    for (int k = 0; k < 3; ++k) {
        r_dm[k] = (d0 > 0) ? x[o_base[k] + (d0 - 1) * PS4] : zero4;
        r_c[k]  = x[o_base[k] + d0 * PS4];
    }
    hvP = hval ? x[hg_base + d0 * PS4] : zero4;    // plane d0 halo
    {
        float4* bw = buf[d0 & 1];
        #pragma unroll
        for (int k = 0; k < 3; ++k) bw[cof[k]] = r_c[k];
        if (hact) bw[hl_off] = hvP;
    }
    // issue plane d0+1 (d0 <= 168, so always in range)
    #pragma unroll
    for (int k = 0; k < 3; ++k) nxP[k] = x[o_base[k] + (d0 + 1) * PS4];
    hvP = hval ? x[hg_base + (d0 + 1) * PS4] : zero4;
    __syncthreads();

    // -------- main D-march --------
    for (int d = d0; d < d0 + TD; ++d) {
        // (1) issue loads for plane d+2 (consumed & committed at step d+1)
        const int  pl2   = d + 2;
        const bool issue = (pl2 <= d0 + TD) && (pl2 < 192);
        float4 nxN[3], hvN;
        if (issue) {
            #pragma unroll
            for (int k = 0; k < 3; ++k) nxN[k] = x[o_base[k] + pl2 * PS4];
            hvN = hval ? x[hg_base + pl2 * PS4] : zero4;
        } else {
            #pragma unroll
            for (int k = 0; k < 3; ++k) nxN[k] = zero4;
            hvN = zero4;
        }

        // (2) compute step d: halos from LDS plane d, dm/c from regs, dp from nxP
        const float4* __restrict__ bc = buf[d & 1];
        #pragma unroll
        for (int k = 0; k < 3; ++k) {
            float4 dp = nxP[k];
            float4 hm = bc[mof[k]];
            float4 hp = bc[pof[k]];
            float4 cl = bc[cof[k] - 1];
            float4 cr = bc[cof[k] + 1];
            float4 c = r_c[k], dm = r_dm[k];
            nfloat4 o4;
            o4.x = c0 * c.x + cc * ((dm.x + dp.x) + (hm.x + hp.x) + (cl.w + c.y));
            o4.y = c0 * c.y + cc * ((dm.y + dp.y) + (hm.y + hp.y) + (c.x  + c.z));
            o4.z = c0 * c.z + cc * ((dm.z + dp.z) + (hm.z + hp.z) + (c.y  + c.w));
            o4.w = c0 * c.w + cc * ((dm.w + dp.w) + (hm.w + hp.w) + (c.z  + cr.x));
            __builtin_nontemporal_store(
                o4, reinterpret_cast<nfloat4*>(&out[o_base[k] + d * PS4]));
            r_dm[k] = c;
            r_c[k]  = dp;
        }

        // (3) commit plane d+1 (loaded last step) into the other buffer
        float4* bw = buf[(d + 1) & 1];
        #pragma unroll
        for (int k = 0; k < 3; ++k) bw[cof[k]] = nxP[k];
        if (hact) bw[hl_off] = hvP;
        __syncthreads();

        // (4) rotate prefetch registers
        #pragma unroll
        for (int k = 0; k < 3; ++k) nxP[k] = nxN[k];
        hvP = hvN;
    }
}

extern "C" void kernel_launch(void* const* d_in, const int* in_sizes, int n_in,
                              void* d_out, int out_size, void* d_ws, size_t ws_size,
                              hipStream_t stream)
{
    const float4* x = (const float4*)d_in[0];
    float4* o = (float4*)d_out;
    dim3 grid(NH, ND, 8);   // 12 x 8 x 8 = 768 blocks = exactly 3/CU
    lap3d_kernel<<<grid, dim3(256), 0, stream>>>(x, o);
}